// Round 4
// baseline (467.667 us; speedup 1.0000x reference)
//
#include <hip/hip_runtime.h>
#include <hip/hip_bf16.h>
#include <math.h>

// ---------------------------------------------------------------------------
// BitNet-b1.58 MLP: x -> bitlinear(W1,b1) -> gelu(erf) -> bitlinear(W2,b2)
// Exact-integer formulation: int8 x int8 -> int32 MFMA, dequant in epilogue.
// GEMM r4: 256x256 tile, BK=128, 8 waves, dbuf LDS, LOOSE schedule:
// only 2 barriers per K-tile (boundary + pre-STAGE_B write hazard), waves
// free-run across sub-phases so ds_read and MFMA overlap cross-wave.
// Counted vmcnt(4) never drains mid-loop. Transposed-C epilogue (swapped
// MFMA operands) for vectorized stores.
// ---------------------------------------------------------------------------

typedef int int32x4 __attribute__((ext_vector_type(4)));

typedef const void __attribute__((address_space(1))) gv_t;
typedef void __attribute__((address_space(3))) lv_t;

__device__ __forceinline__ void gload_lds16(const signed char* g,
                                            signed char* l) {
  __builtin_amdgcn_global_load_lds((gv_t*)g, (lv_t*)l, 16, 0, 0);
}

__device__ __forceinline__ float gelu_erf(float v) {
  return 0.5f * v * (1.0f + erff(v * 0.70710678118654752440f));
}

__device__ __forceinline__ unsigned short bf16_rne(float v) {
  unsigned u = __float_as_uint(v);
  u += 0x7fffu + ((u >> 16) & 1u);
  return (unsigned short)(u >> 16);
}

__device__ __forceinline__ void store4(float* p, const float o[4]) {
  float4 t; t.x = o[0]; t.y = o[1]; t.z = o[2]; t.w = o[3];
  *(float4*)p = t;
}
__device__ __forceinline__ void store4(__hip_bfloat16* p, const float o[4]) {
  ushort4 t;
  t.x = bf16_rne(o[0]); t.y = bf16_rne(o[1]);
  t.z = bf16_rne(o[2]); t.w = bf16_rne(o[3]);
  *(ushort4*)p = t;
}

__device__ __forceinline__ void load4v(const float* p, float v[4]) {
  const float4 t = *(const float4*)p;
  v[0] = t.x; v[1] = t.y; v[2] = t.z; v[3] = t.w;
}
__device__ __forceinline__ void load4v(const __hip_bfloat16* p, float v[4]) {
  const ushort4 t = *(const ushort4*)p;
  v[0] = __uint_as_float((unsigned)t.x << 16);
  v[1] = __uint_as_float((unsigned)t.y << 16);
  v[2] = __uint_as_float((unsigned)t.z << 16);
  v[3] = __uint_as_float((unsigned)t.w << 16);
}

// --------------------------- w_scale reduction ------------------------------
__global__ __launch_bounds__(256) void absmean_partial(
    const float* __restrict__ W, double* __restrict__ part) {
  const int tid = threadIdx.x;
  const long base = (long)blockIdx.x * 8192;
  double s = 0.0;
#pragma unroll
  for (int c = 0; c < 8; ++c) {
    const float4 v = *(const float4*)&W[base + c * 1024 + tid * 4];
    s += (double)fabsf(v.x) + (double)fabsf(v.y) +
         (double)fabsf(v.z) + (double)fabsf(v.w);
  }
  __shared__ double sm[256];
  sm[tid] = s; __syncthreads();
  for (int off = 128; off; off >>= 1) {
    if (tid < off) sm[tid] += sm[tid + off];
    __syncthreads();
  }
  if (tid == 0) part[blockIdx.x] = sm[0];
}

__global__ __launch_bounds__(256) void absmean_final(
    const double* __restrict__ part, double* __restrict__ out, double n) {
  const int tid = threadIdx.x;
  __shared__ double sm[256];
  sm[tid] = part[tid] + part[tid + 256];
  __syncthreads();
  for (int off = 128; off; off >>= 1) {
    if (tid < off) sm[tid] += sm[tid + off];
    __syncthreads();
  }
  if (tid == 0) out[0] = fmax(sm[0] / n, 1e-5);
}

// --------------------------- weight ternarization ---------------------------
__global__ __launch_bounds__(256) void quant_w(
    const float* __restrict__ W, const double* __restrict__ wsP,
    signed char* __restrict__ Wq) {
  const double ws = *wsP;
  const long i = ((long)blockIdx.x * 256 + threadIdx.x) * 4;
  const float4 v = *(const float4*)&W[i];
  const float vv[4] = {v.x, v.y, v.z, v.w};
  int pack = 0;
#pragma unroll
  for (int q = 0; q < 4; ++q) {
    double r = rint((double)vv[q] / ws);  // RNE, matches jnp.round
    r = fmin(fmax(r, -1.0), 1.0);
    pack |= (((int)r) & 0xff) << (8 * q);
  }
  *(int*)&Wq[i] = pack;
}

// --------------------------- per-token activation quant ---------------------
template <int L, bool GELU, typename GT>
__global__ __launch_bounds__(256) void quant_rows(
    const GT* __restrict__ X, signed char* __restrict__ Xq,
    float* __restrict__ dsc) {
  constexpr int CH = L / 1024;
  const long row = blockIdx.x;
  const int tid = threadIdx.x;
  const GT* xr = X + row * (long)L;
  float v[CH][4];
  float m = 0.f;
#pragma unroll
  for (int c = 0; c < CH; ++c) {
    load4v(xr + c * 1024 + tid * 4, v[c]);
#pragma unroll
    for (int q = 0; q < 4; ++q) {
      if (GELU) v[c][q] = gelu_erf(v[c][q]);
      m = fmaxf(m, fabsf(v[c][q]));
    }
  }
#pragma unroll
  for (int off = 32; off; off >>= 1) m = fmaxf(m, __shfl_down(m, off, 64));
  __shared__ float wmx[4];
  if ((tid & 63) == 0) wmx[tid >> 6] = m;
  __syncthreads();
  float ms = fmaxf(fmaxf(wmx[0], wmx[1]), fmaxf(wmx[2], wmx[3]));
  ms = fmaxf(ms, 1e-5f);
  const double inv = 127.0 / (double)ms;
#pragma unroll
  for (int c = 0; c < CH; ++c) {
    int pack = 0;
#pragma unroll
    for (int q = 0; q < 4; ++q) {
      double r = rint((double)v[c][q] * inv);
      r = fmin(fmax(r, -128.0), 127.0);
      pack |= (((int)r) & 0xff) << (8 * q);
    }
    *(int*)&Xq[row * (long)L + c * 1024 + tid * 4] = pack;
  }
  if (tid == 0) dsc[row] = (float)((double)ms / 127.0);
}

// --------------------------- int8 GEMM, loose-sync --------------------------
// C[M][N] = A[M][K] * Bm[N][K]^T. LDS: A dbuf [0,64K), B dbuf [64K,128K).
// Tile = 256 rows x 128 B. Swizzle: col ^= (row&7)<<4 (involution).
// Barrier plan per tile: (1) boundary [vmcnt counted + barrier];
// (2) pre-STAGE_B [lgkmcnt(0) + barrier] — B(t+2) overwrites the B slot
// currently being read, so all waves' B reads must be retired first.
template <typename GT>
__global__ __launch_bounds__(512, 2) void gemm_i8_ls(
    const signed char* __restrict__ A, const signed char* __restrict__ Bm,
    const float* __restrict__ dA, const double* __restrict__ wsB,
    const float* __restrict__ bias, GT* __restrict__ C,
    int K, int Ncol, int nx) {
  __shared__ signed char LDS[131072];
  const int tid = threadIdx.x;
  const int lane = tid & 63;
  const int wave = tid >> 6;
  const int wm = wave >> 2;  // 0..1
  const int wn = wave & 3;   // 0..3

  const int cpx = gridDim.x >> 3;
  const int wg = ((int)blockIdx.x & 7) * cpx + ((int)blockIdx.x >> 3);
  const long rowBase = (long)(wg / nx) * 256;
  const long colBase = (long)(wg % nx) * 256;
  const int NT = K >> 7;  // BK = 128

  // ---- staging: 8 x 16B per thread per K-tile (4 per matrix) ----
  const int dd = tid << 4;                               // [0,8192)
  const int srow = dd >> 7;                              // 0..63
  const int scol = (dd & 127) ^ ((srow & 7) << 4);       // pre-swizzled col
  const long k64 = 64L * K;
  const signed char* sA0 = A + (rowBase + srow) * (long)K + scol;
  const signed char* sB0 = Bm + (colBase + srow) * (long)K + scol;

  // Stage half of the A tile (rows 128h..128h+128) for K-tile t.
  auto STAGE_A2 = [&](int t, int h) {
    const signed char* p = sA0 + ((long)t << 7) + (2 * h) * k64;
    signed char* l = &LDS[((t & 1) << 15) + dd + h * 16384];
    gload_lds16(p, l);
    gload_lds16(p + k64, l + 8192);
  };
  auto STAGE_B4 = [&](int t) {
    const signed char* p = sB0 + ((long)t << 7);
    signed char* l = &LDS[65536 + ((t & 1) << 15) + dd];
#pragma unroll
    for (int i = 0; i < 4; ++i) gload_lds16(p + i * k64, l + i * 8192);
  };

  // ---- ds_read fragment addressing ----
  const int rl = lane & 15;
  const int col0 = (((lane >> 4) << 4)) ^ ((rl & 7) << 4);  // swizzled col, kc0
  const int aRow = wm * 16384 + rl * 128;  // within A tile
  const int bRow = wn * 8192 + rl * 128;   // within B tile

  int32x4 acc[8][4] = {};

  // ---- prologue: B(0), A(0), B(1) staged ----
  STAGE_B4(0);
  STAGE_A2(0, 0); STAGE_A2(0, 1);
  STAGE_B4(1);

  for (int t = 0; t < NT; ++t) {
    // boundary: everything older than the newest 4 loads (B(t+1)) is done
    if (t + 1 < NT) asm volatile("s_waitcnt vmcnt(4)" ::: "memory");
    else            asm volatile("s_waitcnt vmcnt(0)" ::: "memory");
    __builtin_amdgcn_s_barrier();

    const signed char* At = &LDS[(t & 1) << 15];
    const signed char* Bt = &LDS[65536 + ((t & 1) << 15)];
    int32x4 af[4], bf[4];

    auto LDA = [&](int mih, int kc6) {
#pragma unroll
      for (int i = 0; i < 4; ++i)
        af[i] = *(const int32x4*)(At + aRow + (mih * 4 + i) * 2048 +
                                  (col0 ^ kc6));
    };
    auto LDB = [&](int kc6) {
#pragma unroll
      for (int nj = 0; nj < 4; ++nj)
        bf[nj] = *(const int32x4*)(Bt + bRow + nj * 2048 + (col0 ^ kc6));
    };
    // Transposed product: mfma(bf, af) -> lane&15 = M-row, reg-quad = N-col.
    auto MFMA16 = [&](int mih) {
      __builtin_amdgcn_s_setprio(1);
#pragma unroll
      for (int i = 0; i < 4; ++i)
#pragma unroll
        for (int nj = 0; nj < 4; ++nj)
          acc[mih * 4 + i][nj] = __builtin_amdgcn_mfma_i32_16x16x64_i8(
              bf[nj], af[i], acc[mih * 4 + i][nj], 0, 0, 0);
      __builtin_amdgcn_s_setprio(0);
    };

    // ---- free-run region: no barriers, waves drift -> read/MFMA overlap ----
    LDB(0);
    LDA(0, 0);
    if (t + 1 < NT) STAGE_A2(t + 1, 0);
    MFMA16(0);
    LDA(1, 0);
    if (t + 1 < NT) STAGE_A2(t + 1, 1);
    MFMA16(1);
    LDB(64);
    LDA(0, 64);
    MFMA16(0);
    // ---- hazard fence: B(t) reads retired in all waves before STAGE_B ----
    asm volatile("s_waitcnt lgkmcnt(0)" ::: "memory");
    __builtin_amdgcn_s_barrier();
    LDA(1, 64);
    if (t + 2 < NT) STAGE_B4(t + 2);
    MFMA16(1);
  }

  // ---- epilogue (transposed C/D): lane&15 = M-row, (lane>>4)*4+r = N-col --
  const double wsd = *wsB;
  const int rq4 = (lane >> 4) << 2;
  float sc[8];
#pragma unroll
  for (int mi = 0; mi < 8; ++mi)
    sc[mi] = (float)((double)dA[rowBase + wm * 128 + mi * 16 + rl] * wsd);
  float4 bv[4];
#pragma unroll
  for (int nj = 0; nj < 4; ++nj)
    bv[nj] = *(const float4*)&bias[colBase + wn * 64 + nj * 16 + rq4];
#pragma unroll
  for (int mi = 0; mi < 8; ++mi) {
    const long row = rowBase + wm * 128 + mi * 16 + rl;
    GT* crow = C + row * (long)Ncol + colBase + wn * 64 + rq4;
#pragma unroll
    for (int nj = 0; nj < 4; ++nj) {
      float o[4];
      o[0] = (float)acc[mi][nj][0] * sc[mi] + bv[nj].x;
      o[1] = (float)acc[mi][nj][1] * sc[mi] + bv[nj].y;
      o[2] = (float)acc[mi][nj][2] * sc[mi] + bv[nj].z;
      o[3] = (float)acc[mi][nj][3] * sc[mi] + bv[nj].w;
      store4(&crow[nj * 16], o);
    }
  }
}

// ---------------------------------------------------------------------------
extern "C" void kernel_launch(void* const* d_in, const int* in_sizes, int n_in,
                              void* d_out, int out_size, void* d_ws,
                              size_t ws_size, hipStream_t stream) {
  const float* x  = (const float*)d_in[0];
  const float* W1 = (const float*)d_in[1];
  const float* b1 = (const float*)d_in[2];
  const float* W2 = (const float*)d_in[3];
  const float* b2 = (const float*)d_in[4];
  const int D = in_sizes[4];             // 1024
  const int H = in_sizes[2];             // 4096
  const long M = (long)in_sizes[0] / D;  // 32768
  float* out = (float*)d_out;

  if (D != 1024 || H != 4096 || (M % 256) != 0) return;  // shape contract

  char* wsp = (char*)d_ws;
  size_t off = 0;
  auto alloc = [&](size_t bytes) {
    void* p = wsp + off;
    off = (off + bytes + 255) & ~(size_t)255;
    return p;
  };
  signed char* wq1 = (signed char*)alloc((size_t)H * D);
  signed char* wq2 = (signed char*)alloc((size_t)D * H);
  signed char* xq  = (signed char*)alloc((size_t)M * D);
  signed char* gq  = (signed char*)alloc((size_t)M * H);
  float* dx = (float*)alloc((size_t)M * 4);
  float* dg = (float*)alloc((size_t)M * 4);
  double* part = (double*)alloc(512 * 8);
  double* ws1 = (double*)alloc(8);
  double* ws2 = (double*)alloc(8);
  __hip_bfloat16* h = (__hip_bfloat16*)alloc((size_t)M * H * 2);
  if (off > ws_size) return;  // cannot run

  const long nW = (long)H * D;
  absmean_partial<<<nW / 8192, 256, 0, stream>>>(W1, part);
  absmean_final<<<1, 256, 0, stream>>>(part, ws1, (double)nW);
  absmean_partial<<<nW / 8192, 256, 0, stream>>>(W2, part);
  absmean_final<<<1, 256, 0, stream>>>(part, ws2, (double)nW);
  quant_w<<<nW / 1024, 256, 0, stream>>>(W1, ws1, wq1);
  quant_w<<<nW / 1024, 256, 0, stream>>>(W2, ws2, wq2);
  quant_rows<1024, false, float><<<M, 256, 0, stream>>>(x, xq, dx);

  const int g1 = (H / 256) * (int)(M / 256);  // 2048
  const int g2 = (D / 256) * (int)(M / 256);  // 512
  gemm_i8_ls<__hip_bfloat16><<<g1, 512, 0, stream>>>(
      xq, wq1, dx, ws1, b1, h, D, H, H / 256);
  quant_rows<4096, true, __hip_bfloat16><<<M, 256, 0, stream>>>(h, gq, dg);
  gemm_i8_ls<float><<<g2, 512, 0, stream>>>(
      gq, wq2, dg, ws2, b2, out, H, D, D / 256);
}